// Round 16
// baseline (672.761 us; speedup 1.0000x reference)
//
#include <hip/hip_runtime.h>
#include <hip/hip_fp16.h>
#include <math.h>

#define NB 16
#define TT 256
#define JJ 17
#define CC 512
#define HH 8
#define HD 64
#define MROWS (NB*TT*JJ)        // 69632
#define QTILE 16384             // u16 elems per (b,h,j) tile
#define NTILES (NB*HH*JJ)       // 2176
#define NQKV 35651584           // elements per plane (MROWS*512)

#define W0 0.0245436926061702596f   // 2*pi/256

typedef __attribute__((ext_vector_type(8))) short i16x8;
typedef __attribute__((ext_vector_type(8))) _Float16 f16x8;
typedef __attribute__((ext_vector_type(4))) float f32x4;

__device__ __forceinline__ unsigned short f2h(float f) {
    return (unsigned short)__half_as_ushort(__float2half(f));
}
__device__ __forceinline__ float h2f(unsigned short u) {
    return __half2float(__ushort_as_half(u));
}

#define GLD16(gp, lp) __builtin_amdgcn_global_load_lds( \
    (__attribute__((address_space(1))) void*)(gp), \
    (__attribute__((address_space(3))) void*)(lp), 16, 0, 0)

// ---------------- f32 -> f16 conversion (8-wide) ----------------------------
__global__ __launch_bounds__(256) void conv16_k(
    const float* __restrict__ s, unsigned short* __restrict__ d, int n8)
{
    for (int i = blockIdx.x*256 + threadIdx.x; i < n8; i += gridDim.x*256) {
        float4 a = ((const float4*)s)[i*2];
        float4 b = ((const float4*)s)[i*2+1];
        i16x8 h;
        h[0] = (short)f2h(a.x); h[1] = (short)f2h(a.y);
        h[2] = (short)f2h(a.z); h[3] = (short)f2h(a.w);
        h[4] = (short)f2h(b.x); h[5] = (short)f2h(b.y);
        h[6] = (short)f2h(b.z); h[7] = (short)f2h(b.w);
        ((i16x8*)d)[i] = h;
    }
}

// ---------------- fused prep: wq/wp conv + W + WI twiddle init --------------
__global__ __launch_bounds__(256) void prep_k(
    const float* __restrict__ wq, const float* __restrict__ wp,
    unsigned short* __restrict__ wqh, unsigned short* __restrict__ wph,
    unsigned short* __restrict__ Whi, unsigned short* __restrict__ Wlo,
    unsigned short* __restrict__ WIhi)
{
    const int b = blockIdx.x;
    const int tid = threadIdx.x;
    if (b < 512) {
        const float* s = (b < 384) ? wq : wp;
        unsigned short* d = (b < 384) ? wqh : wph;
        int i = (b < 384 ? b : b - 384)*256 + tid;
        float4 a = ((const float4*)s)[i*2];
        float4 bb = ((const float4*)s)[i*2+1];
        i16x8 h;
        h[0] = (short)f2h(a.x); h[1] = (short)f2h(a.y);
        h[2] = (short)f2h(a.z); h[3] = (short)f2h(a.w);
        h[4] = (short)f2h(bb.x); h[5] = (short)f2h(bb.y);
        h[6] = (short)f2h(bb.z); h[7] = (short)f2h(bb.w);
        ((i16x8*)d)[i] = h;
    } else if (b < 640) {
        const int r = b - 512;
        const int t = tid;
        int idx = ((r & 63) * t) & 255;
        float sv, cv;
        sincosf(W0 * (float)idx, &sv, &cv);
        float val = (r < 64) ? cv : -sv;
        unsigned short h = f2h(val);
        Whi[r*256 + t] = h;
        Wlo[r*256 + t] = f2h(val - h2f(h));
    } else {
        int idx = (b - 640)*256 + tid;
        int t = idx >> 7;
        int f = idx & 127;
        int fr = f & 63;
        int ii = (t * fr) & 255;
        float sv, cv;
        sincosf(W0 * (float)ii, &sv, &cv);
        float cf = (fr == 0 && f < 64) ? 0.5f : 1.f;
        float val = ((f < 64) ? cv : -sv) * cf * (2.f / 256.f);
        WIhi[t*128 + f] = f2h(val);
    }
}

// ---------------- GEMM 1 (f16 MFMA, BK=64, 2 col panels per block) ----------
// Grid 3264; each block computes a 128x256 output slab (one plane per block).
// 64 MFMA per barrier-pair; A staged once per K-step for both panels.
__global__ __launch_bounds__(256, 3) void gemm_qkv_k(
    const unsigned short* __restrict__ A, const unsigned short* __restrict__ B,
    unsigned short* __restrict__ qp, unsigned short* __restrict__ kp,
    unsigned short* __restrict__ vp)
{
    __shared__ unsigned short LDS[3*128*64];   // Ah | B1 | B2 ; epilogue Sh=LDS
    unsigned short* Ah = LDS;
    unsigned short* B1 = LDS + 128*64;
    unsigned short* B2 = LDS + 2*128*64;
    const int tid = threadIdx.x;
    const int lane = tid & 63;
    const int lo = lane & 15, hi = lane >> 4;
    const int wv = tid >> 6;
    const int wr = wv >> 1, wc = wv & 1;
    const int bid = blockIdx.x;
    const int wrk = (bid & 7) * 408 + (bid >> 3);   // 3264 = 8*408, bijective
    const int cp   = wrk % 6;
    const int row0 = (wrk / 6) * 128;
    const int col0 = cp * 256;

    f32x4 acc[2][4][4];
    #pragma unroll
    for (int p = 0; p < 2; ++p)
        #pragma unroll
        for (int rb = 0; rb < 4; ++rb)
            #pragma unroll
            for (int cb = 0; cb < 4; ++cb) acc[p][rb][cb] = (f32x4){0.f,0.f,0.f,0.f};

    for (int k0 = 0; k0 < 512; k0 += 64) {
        #pragma unroll
        for (int c = 0; c < 4; ++c) {
            int e = c*2048 + tid*8;
            int r = e >> 6, cc = e & 63;
            int ccs = cc ^ ((r & 7) << 3);
            GLD16(A + (size_t)(row0 + r)*512 + k0 + ccs, (char*)Ah + c*4096 + tid*16);
            GLD16(B + (size_t)(col0 + r)*512 + k0 + ccs, (char*)B1 + c*4096 + tid*16);
            GLD16(B + (size_t)(col0 + 128 + r)*512 + k0 + ccs, (char*)B2 + c*4096 + tid*16);
        }
        __syncthreads();
        #pragma unroll
        for (int ks = 0; ks < 2; ++ks) {
            f16x8 af[4];
            #pragma unroll
            for (int rb = 0; rb < 4; ++rb) {
                int row = wr*64 + rb*16 + lo;
                int col = (ks*32 + hi*8) ^ ((row & 7) << 3);
                af[rb] = *(const f16x8*)&Ah[row*64 + col];
            }
            #pragma unroll
            for (int p = 0; p < 2; ++p) {
                const unsigned short* Bp = p ? B2 : B1;
                f16x8 bf[4];
                #pragma unroll
                for (int cb = 0; cb < 4; ++cb) {
                    int row = wc*64 + cb*16 + lo;
                    int col = (ks*32 + hi*8) ^ ((row & 7) << 3);
                    bf[cb] = *(const f16x8*)&Bp[row*64 + col];
                }
                #pragma unroll
                for (int rb = 0; rb < 4; ++rb)
                    #pragma unroll
                    for (int cb = 0; cb < 4; ++cb)
                        acc[p][rb][cb] = __builtin_amdgcn_mfma_f32_16x16x32_f16(
                            af[rb], bf[cb], acc[p][rb][cb], 0, 0, 0);
            }
        }
        __syncthreads();
    }

    // hoisted m -> (bb, t, j)
    int bbA[8], ttA[8], jjA[8];
    {
        const int grp = lane >> 3;
        #pragma unroll
        for (int it = 0; it < 8; ++it) {
            int p2 = it*32 + wv*8 + grp;
            int row = p2 >> 1;
            int m = row0 + row;
            int bb = m / (TT*JJ);
            int rem = m - bb*(TT*JJ);
            int t = rem / JJ;
            bbA[it] = bb; ttA[it] = t; jjA[it] = rem - t*JJ;
        }
    }

    unsigned short* Sh = LDS;   // 32KB output bounce (Ah|B1 dead)
    #pragma unroll
    for (int p = 0; p < 2; ++p) {
        const int col0p = col0 + p*128;
        #pragma unroll
        for (int cb = 0; cb < 4; ++cb) {
            int n0 = col0p + wc*64 + cb*16;
            float scl = ((n0 >> 9) == 0) ? 0.125f : 1.f;
            #pragma unroll
            for (int rb = 0; rb < 4; ++rb)
                #pragma unroll
                for (int r = 0; r < 4; ++r) {
                    int row = wr*64 + rb*16 + hi*4 + r;
                    int col = wc*64 + cb*16 + lo;
                    Sh[row*128 + (col ^ ((row & 7) << 3))] = f2h(acc[p][rb][cb][r]*scl);
                }
        }
        __syncthreads();
        {
            const int grp = lane >> 3;
            const int d0 = (lane & 7) * 8;
            #pragma unroll
            for (int it = 0; it < 8; ++it) {
                int p2 = it*32 + wv*8 + grp;
                int row = p2 >> 1;
                int half = p2 & 1;
                int n0 = col0p + half*64;
                int g = n0 >> 9;
                unsigned short* dst0 = (g == 0) ? qp : (g == 1) ? kp : vp;
                int h = (n0 >> 6) & 7;
                unsigned short* dst = dst0 +
                    ((((size_t)bbA[it]*HH + h)*JJ + jjA[it])*TT + ttA[it])*HD + d0;
                i16x8 vls = *(const i16x8*)&Sh[row*128 + ((half*64 + d0) ^ ((row & 7) << 3))];
                *(i16x8*)dst = vls;
            }
        }
        __syncthreads();
    }
}

// ---------------- GEMM 2 (f16 MFMA, BK=64): out = y @ w_proj^T + b ----------
__global__ __launch_bounds__(256) void gemm_proj_k(
    const unsigned short* __restrict__ A, const unsigned short* __restrict__ B,
    const float* __restrict__ bias, float* __restrict__ out)
{
    __shared__ unsigned short Ah[128*64];
    __shared__ unsigned short Bh[128*64];
    const int tid = threadIdx.x;
    const int lane = tid & 63;
    const int lo = lane & 15, hi = lane >> 4;
    const int wv = tid >> 6;
    const int wr = wv >> 1, wc = wv & 1;
    const int bid = blockIdx.x;
    const int wrk = (bid & 7) * 272 + (bid >> 3);
    const int col0 = (wrk % 4) * 128;
    const int row0 = (wrk / 4) * 128;

    f32x4 acc[4][4];
    #pragma unroll
    for (int rb = 0; rb < 4; ++rb)
        #pragma unroll
        for (int cb = 0; cb < 4; ++cb) acc[rb][cb] = (f32x4){0.f,0.f,0.f,0.f};

    for (int k0 = 0; k0 < 512; k0 += 64) {
        #pragma unroll
        for (int c = 0; c < 4; ++c) {
            int e = c*2048 + tid*8;
            int r = e >> 6, cc = e & 63;
            int ccs = cc ^ ((r & 7) << 3);
            size_t offA = (size_t)(row0 + r)*512 + k0 + ccs;
            size_t offB = (size_t)(col0 + r)*512 + k0 + ccs;
            GLD16(A + offA, (char*)Ah + c*4096 + tid*16);
            GLD16(B + offB, (char*)Bh + c*4096 + tid*16);
        }
        __syncthreads();
        #pragma unroll
        for (int ks = 0; ks < 2; ++ks) {
            f16x8 af[4], bf[4];
            #pragma unroll
            for (int rb = 0; rb < 4; ++rb) {
                int row = wr*64 + rb*16 + lo;
                int col = (ks*32 + hi*8) ^ ((row & 7) << 3);
                af[rb] = *(const f16x8*)&Ah[row*64 + col];
            }
            #pragma unroll
            for (int cb = 0; cb < 4; ++cb) {
                int row = wc*64 + cb*16 + lo;
                int col = (ks*32 + hi*8) ^ ((row & 7) << 3);
                bf[cb] = *(const f16x8*)&Bh[row*64 + col];
            }
            #pragma unroll
            for (int rb = 0; rb < 4; ++rb)
                #pragma unroll
                for (int cb = 0; cb < 4; ++cb)
                    acc[rb][cb] = __builtin_amdgcn_mfma_f32_16x16x32_f16(
                        af[rb], bf[cb], acc[rb][cb], 0, 0, 0);
        }
        __syncthreads();
    }

    #pragma unroll
    for (int cb = 0; cb < 4; ++cb) {
        int n = col0 + wc*64 + cb*16 + lo;
        float bv = bias[n];
        #pragma unroll
        for (int rb = 0; rb < 4; ++rb)
            #pragma unroll
            for (int r = 0; r < 4; ++r) {
                int m = row0 + wr*64 + rb*16 + hi*4 + r;
                out[(size_t)m*512 + n] = acc[rb][cb][r] + bv;
            }
    }
}

// ---------------- time attention via f16 MFMA (q pre-scaled) ----------------
#define PPW 40

__global__ __launch_bounds__(256, 3) void attn_time_k(
    const unsigned short* __restrict__ q, const unsigned short* __restrict__ k,
    const unsigned short* __restrict__ v, const float* __restrict__ fg,
    unsigned short* __restrict__ y)
{
    __shared__ unsigned short VT[64 * 256];
    __shared__ unsigned short PL[4 * 64 * PPW];

    const int bid = blockIdx.x;
    const int b = bid / (HH*JJ);
    const int h = (bid / JJ) % HH;
    const int j = bid % JJ;
    const size_t base = (size_t)bid * QTILE;

    const int tid = threadIdx.x;
    const int w = tid >> 6;
    const int lane = tid & 63;
    const int lo = lane & 15;
    const int hi = lane >> 4;

    {
        const unsigned short* vptr = v + base + (size_t)tid * HD;
        #pragma unroll
        for (int d0 = 0; d0 < 64; d0 += 8) {
            i16x8 vv = *(const i16x8*)(vptr + d0);
            #pragma unroll
            for (int e = 0; e < 8; ++e) {
                int row = d0 + e;
                VT[row*256 + (tid ^ ((row & 7) << 3))] = (unsigned short)vv[e];
            }
        }
    }
    __syncthreads();

    f16x8 qf[4][2];
    #pragma unroll
    for (int rb = 0; rb < 4; ++rb)
        #pragma unroll
        for (int dc = 0; dc < 2; ++dc)
            qf[rb][dc] = *(const f16x8*)(q + base + (size_t)(w*64 + rb*16 + lo)*HD + dc*32 + hi*8);

    f32x4 o[4][4];
    #pragma unroll
    for (int rb = 0; rb < 4; ++rb)
        #pragma unroll
        for (int cd = 0; cd < 4; ++cd) o[rb][cd] = (f32x4){0.f,0.f,0.f,0.f};
    float rs[4][4];
    #pragma unroll
    for (int rb = 0; rb < 4; ++rb)
        #pragma unroll
        for (int r = 0; r < 4; ++r) rs[rb][r] = 0.f;

    unsigned short* Pw = PL + w * 64 * PPW;

    for (int st = 0; st < 8; ++st) {
        const int s0 = st * 32;
        f16x8 kf[2][2];
        #pragma unroll
        for (int cb = 0; cb < 2; ++cb)
            #pragma unroll
            for (int dc = 0; dc < 2; ++dc)
                kf[cb][dc] = *(const f16x8*)(k + base + (size_t)(s0 + cb*16 + lo)*HD + dc*32 + hi*8);

        #pragma unroll
        for (int rb = 0; rb < 4; ++rb) {
            #pragma unroll
            for (int cb = 0; cb < 2; ++cb) {
                f32x4 acc = (f32x4){0.f,0.f,0.f,0.f};
                acc = __builtin_amdgcn_mfma_f32_16x16x32_f16(qf[rb][0], kf[cb][0], acc, 0, 0, 0);
                acc = __builtin_amdgcn_mfma_f32_16x16x32_f16(qf[rb][1], kf[cb][1], acc, 0, 0, 0);
                #pragma unroll
                for (int r = 0; r < 4; ++r) {
                    float p = __expf(acc[r]);
                    rs[rb][r] += p;
                    Pw[(rb*16 + hi*4 + r)*PPW + cb*16 + lo] = f2h(p);
                }
            }
        }

        f16x8 pa[4];
        #pragma unroll
        for (int rb = 0; rb < 4; ++rb)
            pa[rb] = *(const f16x8*)&Pw[(rb*16 + lo)*PPW + hi*8];
        f16x8 bv[4];
        #pragma unroll
        for (int cd = 0; cd < 4; ++cd) {
            int row = cd*16 + lo;
            bv[cd] = *(const f16x8*)&VT[row*256 + ((s0 + hi*8) ^ ((row & 7) << 3))];
        }
        #pragma unroll
        for (int rb = 0; rb < 4; ++rb)
            #pragma unroll
            for (int cd = 0; cd < 4; ++cd)
                o[rb][cd] = __builtin_amdgcn_mfma_f32_16x16x32_f16(pa[rb], bv[cd], o[rb][cd], 0, 0, 0);
    }

    #pragma unroll
    for (int off = 1; off < 16; off <<= 1)
        #pragma unroll
        for (int rb = 0; rb < 4; ++rb)
            #pragma unroll
            for (int r = 0; r < 4; ++r)
                rs[rb][r] += __shfl_xor(rs[rb][r], off, 64);

    const float gate = 1.f / (1.f + __expf(-fg[0]));
    const float wt = 1.f - gate;
    #pragma unroll
    for (int rb = 0; rb < 4; ++rb) {
        #pragma unroll
        for (int r = 0; r < 4; ++r) {
            const int t = w*64 + rb*16 + hi*4 + r;
            const float sc = wt / rs[rb][r];
            unsigned short* yp = y + (((size_t)b*TT + t)*JJ + j)*CC + h*HD;
            #pragma unroll
            for (int cd = 0; cd < 4; ++cd)
                yp[cd*16 + lo] = f2h(o[rb][cd][r] * sc);
        }
    }
}

// ---------------- F1: DFT MFMA GEMM, f16 in -> f16 freq out in place --------
// V plane (blockIdx.y == 2) uses single-product W (post-softmax linear path).
#define XP 280

__global__ __launch_bounds__(256) void dft_k(
    unsigned short* __restrict__ planes, const unsigned short* __restrict__ Whi,
    const unsigned short* __restrict__ Wlo)
{
    __shared__ unsigned short Xh[64*XP];
    unsigned short* src = planes + (size_t)blockIdx.y*NQKV + (size_t)blockIdx.x*QTILE;
    const bool useLo = (blockIdx.y != 2);
    const int tid = threadIdx.x;
    const int w = tid >> 6;
    const int lane = tid & 63;
    const int qd = (tid >> 4) & 3;
    const int rr = tid & 15;
    const int lo = lane & 15, hi = lane >> 4;

    #pragma unroll
    for (int p = 0; p < 16; ++p) {
        const int t = p*16 + 4*w + qd;
        ushort4 x4 = *(const ushort4*)&src[t*64 + 4*rr];
        unsigned int a0 = x4.x, a1 = x4.y, a2 = x4.z, a3 = x4.w;
        unsigned int t01 = (unsigned)__shfl_xor((int)((qd&1) ? a0 : a1), 16, 64);
        unsigned int t23 = (unsigned)__shfl_xor((int)((qd&1) ? a2 : a3), 16, 64);
        if (qd&1) { a0 = t01; a2 = t23; } else { a1 = t01; a3 = t23; }
        unsigned int u01 = (unsigned)__shfl_xor((int)((qd&2) ? a0 : a2), 32, 64);
        unsigned int u23 = (unsigned)__shfl_xor((int)((qd&2) ? a1 : a3), 32, 64);
        if (qd&2) { a0 = u01; a1 = u23; } else { a2 = u01; a3 = u23; }
        const int dd = 4*rr + qd;
        const int tb = p*16 + 4*w;
        ushort4 hv;
        hv.x = (unsigned short)a0; hv.y = (unsigned short)a1;
        hv.z = (unsigned short)a2; hv.w = (unsigned short)a3;
        *(ushort4*)&Xh[dd*XP + tb] = hv;
    }
    __syncthreads();

    f32x4 acc[2][4];
    #pragma unroll
    for (int rb = 0; rb < 2; ++rb)
        #pragma unroll
        for (int cd = 0; cd < 4; ++cd) acc[rb][cd] = (f32x4){0.f,0.f,0.f,0.f};

    for (int ks = 0; ks < 8; ++ks) {
        const int k0 = ks*32;
        f16x8 ah[2], al[2];
        #pragma unroll
        for (int rb = 0; rb < 2; ++rb) {
            int r = w*32 + rb*16 + lo;
            ah[rb] = *(const f16x8*)&Whi[r*256 + k0 + hi*8];
            if (useLo) al[rb] = *(const f16x8*)&Wlo[r*256 + k0 + hi*8];
        }
        f16x8 bh[4];
        #pragma unroll
        for (int cd = 0; cd < 4; ++cd) {
            int d = cd*16 + lo;
            bh[cd] = *(const f16x8*)&Xh[d*XP + k0 + hi*8];
        }
        #pragma unroll
        for (int rb = 0; rb < 2; ++rb)
            #pragma unroll
            for (int cd = 0; cd < 4; ++cd) {
                acc[rb][cd] = __builtin_amdgcn_mfma_f32_16x16x32_f16(
                    ah[rb], bh[cd], acc[rb][cd], 0, 0, 0);
                if (useLo)
                    acc[rb][cd] = __builtin_amdgcn_mfma_f32_16x16x32_f16(
                        al[rb], bh[cd], acc[rb][cd], 0, 0, 0);
            }
    }

    #pragma unroll
    for (int rb = 0; rb < 2; ++rb) {
        #pragma unroll
        for (int r = 0; r < 4; ++r) {
            int row = w*32 + rb*16 + hi*4 + r;
            unsigned short* dst = (row < 64) ? (src + row*64)
                                             : (src + 4096 + (row-64)*64);
            #pragma unroll
            for (int cd = 0; cd < 4; ++cd)
                dst[cd*16 + lo] = f2h(acc[rb][cd][r]);
        }
    }
}

// ---------------- F2+F3 fused, all-MFMA: af -> in-reg dual softmax ->
// xf -> irfft -> y (round-14 proven structure).
#define FQP 72
#define XFP 136

__global__ __launch_bounds__(256) void freqtail_k(
    const unsigned short* __restrict__ qfp, const unsigned short* __restrict__ kfp,
    const unsigned short* __restrict__ vfp, const unsigned short* __restrict__ WIhi,
    const float* __restrict__ fg, unsigned short* __restrict__ y)
{
    __shared__ unsigned short S1[128*FQP];   // qf -> P -> XT
    __shared__ unsigned short S2[128*FQP];   // kf -> VFT

    const int tid = threadIdx.x;
    const int tile = blockIdx.x;
    const int b = tile / (HH*JJ);
    const int h = (tile / JJ) % HH;
    const int j = tile % JJ;
    const unsigned short* qf = qfp + (size_t)tile * QTILE;
    const unsigned short* kf = kfp + (size_t)tile * QTILE;
    const unsigned short* vf = vfp + (size_t)tile * QTILE;

    const int w = tid >> 6;
    const int lane = tid & 63;
    const int lo = lane & 15, hi = lane >> 4;
    const int comp = w >> 1;
    const int fr0 = (w & 1) * 32;

    #pragma unroll
    for (int p = 0; p < 4; ++p) {
        int e8 = (p*256 + tid) * 8;
        int row = e8 >> 6, col = e8 & 63;
        *(i16x8*)&S1[row*FQP + col] = *(const i16x8*)(qf + e8);
        *(i16x8*)&S2[row*FQP + col] = *(const i16x8*)(kf + e8);
    }
    __syncthreads();

    f32x4 accA[2][4], accB[2][4];
    #pragma unroll
    for (int rb = 0; rb < 2; ++rb)
        #pragma unroll
        for (int cb = 0; cb < 4; ++cb) {
            accA[rb][cb] = (f32x4){0.f,0.f,0.f,0.f};
            accB[rb][cb] = (f32x4){0.f,0.f,0.f,0.f};
        }
    #pragma unroll
    for (int ks = 0; ks < 2; ++ks) {
        f16x8 qA[2], qB[2];
        #pragma unroll
        for (int rb = 0; rb < 2; ++rb) {
            int fr = fr0 + rb*16 + lo;
            qA[rb] = *(const f16x8*)&S1[(comp*64 + fr)*FQP + ks*32 + hi*8];
            qB[rb] = *(const f16x8*)&S1[((1-comp)*64 + fr)*FQP + ks*32 + hi*8];
        }
        f16x8 kr[4], ki[4];
        #pragma unroll
        for (int cb = 0; cb < 4; ++cb) {
            int g = cb*16 + lo;
            kr[cb] = *(const f16x8*)&S2[g*FQP + ks*32 + hi*8];
            ki[cb] = *(const f16x8*)&S2[(64 + g)*FQP + ks*32 + hi*8];
        }
        #pragma unroll
        for (int rb = 0; rb < 2; ++rb)
            #pragma unroll
            for (int cb = 0; cb < 4; ++cb) {
                accA[rb][cb] = __builtin_amdgcn_mfma_f32_16x16x32_f16(
                    qA[rb], kr[cb], accA[rb][cb], 0, 0, 0);
                accB[rb][cb] = __builtin_amdgcn_mfma_f32_16x16x32_f16(
                    qB[rb], ki[cb], accB[rb][cb], 0, 0, 0);
            }
    }
    __syncthreads();

    const float sgn = comp ? -1.f : 1.f;
    float pv[2][4][4];
    float inv[2][4];
    #pragma unroll
    for (int rb = 0; rb < 2; ++rb) {
        #pragma unroll
        for (int r = 0; r < 4; ++r) {
            float m = -3.0e38f;
            #pragma unroll
            for (int cb = 0; cb < 4; ++cb) {
                float vv = accA[rb][cb][r] + sgn*accB[rb][cb][r];
                pv[rb][cb][r] = vv;
                m = fmaxf(m, vv);
            }
            #pragma unroll
            for (int off = 1; off < 16; off <<= 1)
                m = fmaxf(m, __shfl_xor(m, off, 64));
            float s = 0.f;
            #pragma unroll
            for (int cb = 0; cb < 4; ++cb) {
                float e = __expf(pv[rb][cb][r] - m);
                pv[rb][cb][r] = e;
                s += e;
            }
            #pragma unroll
            for (int off = 1; off < 16; off <<= 1)
                s += __shfl_xor(s, off, 64);
            inv[rb][r] = 1.f / s;
        }
    }
    #pragma unroll
    for (int rb = 0; rb < 2; ++rb)
        #pragma unroll
        for (int r = 0; r < 4; ++r)
            #pragma unroll
            for (int cb = 0; cb < 4; ++cb)
                S1[(w*32 + rb*16 + hi*4 + r)*FQP + cb*16 + lo] =
                    f2h(pv[rb][cb][r] * inv[rb][r]);

    #pragma unroll
    for (int p = 0; p < 4; ++p) {
        int e8 = (p*256 + tid) * 8;
        int srow = e8 >> 6;
        int c2 = srow >> 6, g = srow & 63, d0 = e8 & 63;
        i16x8 vv = *(const i16x8*)(vf + e8);
        #pragma unroll
        for (int e = 0; e < 8; ++e)
            S2[(c2*64 + d0 + e)*FQP + g] = (unsigned short)vv[e];
    }
    __syncthreads();

    f32x4 xA[2][4], xB[2][4];
    #pragma unroll
    for (int rb = 0; rb < 2; ++rb)
        #pragma unroll
        for (int cd = 0; cd < 4; ++cd) {
            xA[rb][cd] = (f32x4){0.f,0.f,0.f,0.f};
            xB[rb][cd] = (f32x4){0.f,0.f,0.f,0.f};
        }
    #pragma unroll
    for (int ks = 0; ks < 2; ++ks) {
        f16x8 pA[2], pB[2];
        #pragma unroll
        for (int rb = 0; rb < 2; ++rb) {
            int fr = fr0 + rb*16 + lo;
            pA[rb] = *(const f16x8*)&S1[fr*FQP + ks*32 + hi*8];
            pB[rb] = *(const f16x8*)&S1[(64 + fr)*FQP + ks*32 + hi*8];
        }
        f16x8 bA[4], bB[4];
        #pragma unroll
        for (int cd = 0; cd < 4; ++cd) {
            int d = cd*16 + lo;
            bA[cd] = *(const f16x8*)&S2[(comp*64 + d)*FQP + ks*32 + hi*8];
            bB[cd] = *(const f16x8*)&S2[((1-comp)*64 + d)*FQP + ks*32 + hi*8];
        }
        #pragma unroll
        for (int rb = 0; rb < 2; ++rb)
            #pragma unroll
            for (int cd = 0; cd < 4; ++cd) {
                xA[rb][cd] = __builtin_amdgcn_mfma_f32_16x16x32_f16(
                    pA[rb], bA[cd], xA[rb][cd], 0, 0, 0);
                xB[rb][cd] = __builtin_amdgcn_mfma_f32_16x16x32_f16(
                    pB[rb], bB[cd], xB[rb][cd], 0, 0, 0);
            }
    }
    __syncthreads();

    const float sgn2 = comp ? 1.f : -1.f;
    unsigned short* XT = S1;
    #pragma unroll
    for (int rb = 0; rb < 2; ++rb)
        #pragma unroll
        for (int cd = 0; cd < 4; ++cd)
            #pragma unroll
            for (int r = 0; r < 4; ++r) {
                int f = fr0 + rb*16 + hi*4 + r;
                int d = cd*16 + lo;
                XT[d*XFP + comp*64 + f] =
                    f2h(xA[rb][cd][r] + sgn2*xB[rb][cd][r]);
            }
    __syncthreads();

    f32x4 acc[4][4];
    #pragma unroll
    for (int rb = 0; rb < 4; ++rb)
        #pragma unroll
        for (int cd = 0; cd < 4; ++cd) acc[rb][cd] = (f32x4){0.f,0.f,0.f,0.f};

    #pragma unroll
    for (int ks = 0; ks < 4; ++ks) {
        const int k0 = ks*32;
        f16x8 ah[4];
        #pragma unroll
        for (int rb = 0; rb < 4; ++rb) {
            int row = w*64 + rb*16 + lo;
            ah[rb] = *(const f16x8*)&WIhi[row*128 + k0 + hi*8];
        }
        f16x8 bt[4];
        #pragma unroll
        for (int cd = 0; cd < 4; ++cd) {
            int d = cd*16 + lo;
            bt[cd] = *(const f16x8*)&XT[d*XFP + k0 + hi*8];
        }
        #pragma unroll
        for (int rb = 0; rb < 4; ++rb)
            #pragma unroll
            for (int cd = 0; cd < 4; ++cd)
                acc[rb][cd] = __builtin_amdgcn_mfma_f32_16x16x32_f16(
                    ah[rb], bt[cd], acc[rb][cd], 0, 0, 0);
    }

    const float gate = 1.f / (1.f + __expf(-fg[0]));
    #pragma unroll
    for (int rb = 0; rb < 4; ++rb) {
        #pragma unroll
        for (int r = 0; r < 4; ++r) {
            int t = w*64 + rb*16 + hi*4 + r;
            unsigned short* yp = y + (((size_t)b*TT + t)*JJ + j)*CC + h*HD;
            #pragma unroll
            for (int cd = 0; cd < 4; ++cd) {
                int d = cd*16 + lo;
                yp[d] = f2h(fmaf(gate, acc[rb][cd][r], h2f(yp[d])));
            }
        }
    }
}

// ---------------------------------------------------------------------------
extern "C" void kernel_launch(void* const* d_in, const int* in_sizes, int n_in,
                              void* d_out, int out_size, void* d_ws, size_t ws_size,
                              hipStream_t stream) {
    const float* x      = (const float*)d_in[0];
    const float* w_qkv  = (const float*)d_in[1];
    const float* w_proj = (const float*)d_in[2];
    const float* b_proj = (const float*)d_in[3];
    const float* fg     = (const float*)d_in[4];
    float* out = (float*)d_out;

    unsigned short* qp = (unsigned short*)d_ws;
    unsigned short* kp = qp + NQKV;
    unsigned short* vp = kp + NQKV;
    unsigned short* xh = vp + NQKV;
    unsigned short* y  = xh + NQKV;
    unsigned short* wph = y + NQKV;
    unsigned short* wqh = (unsigned short*)d_out;
    unsigned short* Whi  = wqh + 1536*512;   // 128*256
    unsigned short* Wlo  = Whi + 128*256;
    unsigned short* WIhi = Wlo + 128*256;    // 256*128

    conv16_k<<<2048, 256, 0, stream>>>(x, xh, NQKV/8);
    prep_k<<<768, 256, 0, stream>>>(w_qkv, w_proj, wqh, wph, Whi, Wlo, WIhi);

    gemm_qkv_k<<<3264, 256, 0, stream>>>(xh, wqh, qp, kp, vp);
    attn_time_k<<<NTILES, 256, 0, stream>>>(qp, kp, vp, fg, y);
    dft_k<<<dim3(NTILES, 3), 256, 0, stream>>>(qp, Whi, Wlo);
    freqtail_k<<<NTILES, 256, 0, stream>>>(qp, kp, vp, WIhi, fg, y);

    gemm_proj_k<<<2176, 256, 0, stream>>>(y, wph, b_proj, out);
}

// Round 17
// 589.152 us; speedup vs baseline: 1.1419x; 1.1419x over previous
//
#include <hip/hip_runtime.h>
#include <hip/hip_fp16.h>
#include <math.h>

#define NB 16
#define TT 256
#define JJ 17
#define CC 512
#define HH 8
#define HD 64
#define MROWS (NB*TT*JJ)        // 69632
#define QTILE 16384             // u16 elems per (b,h,j) tile
#define NTILES (NB*HH*JJ)       // 2176
#define NQKV 35651584           // elements per plane (MROWS*512)

#define W0 0.0245436926061702596f   // 2*pi/256

typedef __attribute__((ext_vector_type(8))) short i16x8;
typedef __attribute__((ext_vector_type(8))) _Float16 f16x8;
typedef __attribute__((ext_vector_type(4))) float f32x4;

__device__ __forceinline__ unsigned short f2h(float f) {
    return (unsigned short)__half_as_ushort(__float2half(f));
}
__device__ __forceinline__ float h2f(unsigned short u) {
    return __half2float(__ushort_as_half(u));
}

#define GLD16(gp, lp) __builtin_amdgcn_global_load_lds( \
    (__attribute__((address_space(1))) void*)(gp), \
    (__attribute__((address_space(3))) void*)(lp), 16, 0, 0)

// ---------------- f32 -> f16 conversion (8-wide) ----------------------------
__global__ __launch_bounds__(256) void conv16_k(
    const float* __restrict__ s, unsigned short* __restrict__ d, int n8)
{
    for (int i = blockIdx.x*256 + threadIdx.x; i < n8; i += gridDim.x*256) {
        float4 a = ((const float4*)s)[i*2];
        float4 b = ((const float4*)s)[i*2+1];
        i16x8 h;
        h[0] = (short)f2h(a.x); h[1] = (short)f2h(a.y);
        h[2] = (short)f2h(a.z); h[3] = (short)f2h(a.w);
        h[4] = (short)f2h(b.x); h[5] = (short)f2h(b.y);
        h[6] = (short)f2h(b.z); h[7] = (short)f2h(b.w);
        ((i16x8*)d)[i] = h;
    }
}

// ---------------- fused prep: wq/wp conv + W + WI twiddle init --------------
__global__ __launch_bounds__(256) void prep_k(
    const float* __restrict__ wq, const float* __restrict__ wp,
    unsigned short* __restrict__ wqh, unsigned short* __restrict__ wph,
    unsigned short* __restrict__ Whi, unsigned short* __restrict__ Wlo,
    unsigned short* __restrict__ WIhi)
{
    const int b = blockIdx.x;
    const int tid = threadIdx.x;
    if (b < 512) {
        const float* s = (b < 384) ? wq : wp;
        unsigned short* d = (b < 384) ? wqh : wph;
        int i = (b < 384 ? b : b - 384)*256 + tid;
        float4 a = ((const float4*)s)[i*2];
        float4 bb = ((const float4*)s)[i*2+1];
        i16x8 h;
        h[0] = (short)f2h(a.x); h[1] = (short)f2h(a.y);
        h[2] = (short)f2h(a.z); h[3] = (short)f2h(a.w);
        h[4] = (short)f2h(bb.x); h[5] = (short)f2h(bb.y);
        h[6] = (short)f2h(bb.z); h[7] = (short)f2h(bb.w);
        ((i16x8*)d)[i] = h;
    } else if (b < 640) {
        const int r = b - 512;
        const int t = tid;
        int idx = ((r & 63) * t) & 255;
        float sv, cv;
        sincosf(W0 * (float)idx, &sv, &cv);
        float val = (r < 64) ? cv : -sv;
        unsigned short h = f2h(val);
        Whi[r*256 + t] = h;
        Wlo[r*256 + t] = f2h(val - h2f(h));
    } else {
        int idx = (b - 640)*256 + tid;
        int t = idx >> 7;
        int f = idx & 127;
        int fr = f & 63;
        int ii = (t * fr) & 255;
        float sv, cv;
        sincosf(W0 * (float)ii, &sv, &cv);
        float cf = (fr == 0 && f < 64) ? 0.5f : 1.f;
        float val = ((f < 64) ? cv : -sv) * cf * (2.f / 256.f);
        WIhi[t*128 + f] = f2h(val);
    }
}

// ---------------- GEMM 1 (f16 MFMA, BK=64): qkv = x @ w_qkv^T ---------------
// (round-14 proven configuration: 128x128 tile, grid 6528, LDS-bounce epilogue)
__global__ __launch_bounds__(256) void gemm_qkv_k(
    const unsigned short* __restrict__ A, const unsigned short* __restrict__ B,
    unsigned short* __restrict__ qp, unsigned short* __restrict__ kp,
    unsigned short* __restrict__ vp)
{
    __shared__ unsigned short Sh[128*128];
    unsigned short* Ah = Sh;
    unsigned short* Bh = Sh + 128*64;
    const int tid = threadIdx.x;
    const int lane = tid & 63;
    const int lo = lane & 15, hi = lane >> 4;
    const int wv = tid >> 6;
    const int wr = wv >> 1, wc = wv & 1;
    const int bid = blockIdx.x;
    const int wrk = (bid & 7) * 816 + (bid >> 3);
    const int col0 = (wrk % 12) * 128;
    const int row0 = (wrk / 12) * 128;

    f32x4 acc[4][4];
    #pragma unroll
    for (int rb = 0; rb < 4; ++rb)
        #pragma unroll
        for (int cb = 0; cb < 4; ++cb) acc[rb][cb] = (f32x4){0.f,0.f,0.f,0.f};

    for (int k0 = 0; k0 < 512; k0 += 64) {
        #pragma unroll
        for (int c = 0; c < 4; ++c) {
            int e = c*2048 + tid*8;
            int r = e >> 6, cc = e & 63;
            int ccs = cc ^ ((r & 7) << 3);
            size_t offA = (size_t)(row0 + r)*512 + k0 + ccs;
            size_t offB = (size_t)(col0 + r)*512 + k0 + ccs;
            GLD16(A + offA, (char*)Ah + c*4096 + tid*16);
            GLD16(B + offB, (char*)Bh + c*4096 + tid*16);
        }
        __syncthreads();
        #pragma unroll
        for (int ks = 0; ks < 2; ++ks) {
            f16x8 af[4], bf[4];
            #pragma unroll
            for (int rb = 0; rb < 4; ++rb) {
                int row = wr*64 + rb*16 + lo;
                int col = (ks*32 + hi*8) ^ ((row & 7) << 3);
                af[rb] = *(const f16x8*)&Ah[row*64 + col];
            }
            #pragma unroll
            for (int cb = 0; cb < 4; ++cb) {
                int row = wc*64 + cb*16 + lo;
                int col = (ks*32 + hi*8) ^ ((row & 7) << 3);
                bf[cb] = *(const f16x8*)&Bh[row*64 + col];
            }
            #pragma unroll
            for (int rb = 0; rb < 4; ++rb)
                #pragma unroll
                for (int cb = 0; cb < 4; ++cb)
                    acc[rb][cb] = __builtin_amdgcn_mfma_f32_16x16x32_f16(
                        af[rb], bf[cb], acc[rb][cb], 0, 0, 0);
        }
        __syncthreads();
    }

    #pragma unroll
    for (int cb = 0; cb < 4; ++cb) {
        int n0 = col0 + wc*64 + cb*16;
        float scl = ((n0 >> 9) == 0) ? 0.125f : 1.f;
        #pragma unroll
        for (int rb = 0; rb < 4; ++rb)
            #pragma unroll
            for (int r = 0; r < 4; ++r) {
                int row = wr*64 + rb*16 + hi*4 + r;
                int col = wc*64 + cb*16 + lo;
                Sh[row*128 + (col ^ ((row & 7) << 3))] = f2h(acc[rb][cb][r]*scl);
            }
    }
    __syncthreads();

    {
        const int grp = lane >> 3;
        const int d0 = (lane & 7) * 8;
        #pragma unroll
        for (int it = 0; it < 8; ++it) {
            int p = it*32 + wv*8 + grp;
            int row = p >> 1;
            int half = p & 1;
            int m = row0 + row;
            int bb = m / (TT*JJ);
            int rem = m - bb*(TT*JJ);
            int t = rem / JJ;
            int j = rem - t*JJ;
            int n0 = col0 + half*64;
            int g = n0 >> 9;
            unsigned short* dst0 = (g == 0) ? qp : (g == 1) ? kp : vp;
            int h = (n0 >> 6) & 7;
            unsigned short* dst = dst0 +
                ((((size_t)bb*HH + h)*JJ + j)*TT + t)*HD + d0;
            i16x8 vls = *(const i16x8*)&Sh[row*128 + ((half*64 + d0) ^ ((row & 7) << 3))];
            *(i16x8*)dst = vls;
        }
    }
}

// ---------------- GEMM 2 (f16 MFMA, BK=64): out = y @ w_proj^T + b ----------
__global__ __launch_bounds__(256) void gemm_proj_k(
    const unsigned short* __restrict__ A, const unsigned short* __restrict__ B,
    const float* __restrict__ bias, float* __restrict__ out)
{
    __shared__ unsigned short Ah[128*64];
    __shared__ unsigned short Bh[128*64];
    const int tid = threadIdx.x;
    const int lane = tid & 63;
    const int lo = lane & 15, hi = lane >> 4;
    const int wv = tid >> 6;
    const int wr = wv >> 1, wc = wv & 1;
    const int bid = blockIdx.x;
    const int wrk = (bid & 7) * 272 + (bid >> 3);
    const int col0 = (wrk % 4) * 128;
    const int row0 = (wrk / 4) * 128;

    f32x4 acc[4][4];
    #pragma unroll
    for (int rb = 0; rb < 4; ++rb)
        #pragma unroll
        for (int cb = 0; cb < 4; ++cb) acc[rb][cb] = (f32x4){0.f,0.f,0.f,0.f};

    for (int k0 = 0; k0 < 512; k0 += 64) {
        #pragma unroll
        for (int c = 0; c < 4; ++c) {
            int e = c*2048 + tid*8;
            int r = e >> 6, cc = e & 63;
            int ccs = cc ^ ((r & 7) << 3);
            size_t offA = (size_t)(row0 + r)*512 + k0 + ccs;
            size_t offB = (size_t)(col0 + r)*512 + k0 + ccs;
            GLD16(A + offA, (char*)Ah + c*4096 + tid*16);
            GLD16(B + offB, (char*)Bh + c*4096 + tid*16);
        }
        __syncthreads();
        #pragma unroll
        for (int ks = 0; ks < 2; ++ks) {
            f16x8 af[4], bf[4];
            #pragma unroll
            for (int rb = 0; rb < 4; ++rb) {
                int row = wr*64 + rb*16 + lo;
                int col = (ks*32 + hi*8) ^ ((row & 7) << 3);
                af[rb] = *(const f16x8*)&Ah[row*64 + col];
            }
            #pragma unroll
            for (int cb = 0; cb < 4; ++cb) {
                int row = wc*64 + cb*16 + lo;
                int col = (ks*32 + hi*8) ^ ((row & 7) << 3);
                bf[cb] = *(const f16x8*)&Bh[row*64 + col];
            }
            #pragma unroll
            for (int rb = 0; rb < 4; ++rb)
                #pragma unroll
                for (int cb = 0; cb < 4; ++cb)
                    acc[rb][cb] = __builtin_amdgcn_mfma_f32_16x16x32_f16(
                        af[rb], bf[cb], acc[rb][cb], 0, 0, 0);
        }
        __syncthreads();
    }

    #pragma unroll
    for (int cb = 0; cb < 4; ++cb) {
        int n = col0 + wc*64 + cb*16 + lo;
        float bv = bias[n];
        #pragma unroll
        for (int rb = 0; rb < 4; ++rb)
            #pragma unroll
            for (int r = 0; r < 4; ++r) {
                int m = row0 + wr*64 + rb*16 + hi*4 + r;
                out[(size_t)m*512 + n] = acc[rb][cb][r] + bv;
            }
    }
}

// ---------------- time attention via f16 MFMA (q pre-scaled) ----------------
#define PPW 40

__global__ __launch_bounds__(256, 3) void attn_time_k(
    const unsigned short* __restrict__ q, const unsigned short* __restrict__ k,
    const unsigned short* __restrict__ v, const float* __restrict__ fg,
    unsigned short* __restrict__ y)
{
    __shared__ unsigned short VT[64 * 256];
    __shared__ unsigned short PL[4 * 64 * PPW];

    const int bid = blockIdx.x;
    const int b = bid / (HH*JJ);
    const int h = (bid / JJ) % HH;
    const int j = bid % JJ;
    const size_t base = (size_t)bid * QTILE;

    const int tid = threadIdx.x;
    const int w = tid >> 6;
    const int lane = tid & 63;
    const int lo = lane & 15;
    const int hi = lane >> 4;

    {
        const unsigned short* vptr = v + base + (size_t)tid * HD;
        #pragma unroll
        for (int d0 = 0; d0 < 64; d0 += 8) {
            i16x8 vv = *(const i16x8*)(vptr + d0);
            #pragma unroll
            for (int e = 0; e < 8; ++e) {
                int row = d0 + e;
                VT[row*256 + (tid ^ ((row & 7) << 3))] = (unsigned short)vv[e];
            }
        }
    }
    __syncthreads();

    f16x8 qf[4][2];
    #pragma unroll
    for (int rb = 0; rb < 4; ++rb)
        #pragma unroll
        for (int dc = 0; dc < 2; ++dc)
            qf[rb][dc] = *(const f16x8*)(q + base + (size_t)(w*64 + rb*16 + lo)*HD + dc*32 + hi*8);

    f32x4 o[4][4];
    #pragma unroll
    for (int rb = 0; rb < 4; ++rb)
        #pragma unroll
        for (int cd = 0; cd < 4; ++cd) o[rb][cd] = (f32x4){0.f,0.f,0.f,0.f};
    float rs[4][4];
    #pragma unroll
    for (int rb = 0; rb < 4; ++rb)
        #pragma unroll
        for (int r = 0; r < 4; ++r) rs[rb][r] = 0.f;

    unsigned short* Pw = PL + w * 64 * PPW;

    for (int st = 0; st < 8; ++st) {
        const int s0 = st * 32;
        f16x8 kf[2][2];
        #pragma unroll
        for (int cb = 0; cb < 2; ++cb)
            #pragma unroll
            for (int dc = 0; dc < 2; ++dc)
                kf[cb][dc] = *(const f16x8*)(k + base + (size_t)(s0 + cb*16 + lo)*HD + dc*32 + hi*8);

        #pragma unroll
        for (int rb = 0; rb < 4; ++rb) {
            #pragma unroll
            for (int cb = 0; cb < 2; ++cb) {
                f32x4 acc = (f32x4){0.f,0.f,0.f,0.f};
                acc = __builtin_amdgcn_mfma_f32_16x16x32_f16(qf[rb][0], kf[cb][0], acc, 0, 0, 0);
                acc = __builtin_amdgcn_mfma_f32_16x16x32_f16(qf[rb][1], kf[cb][1], acc, 0, 0, 0);
                #pragma unroll
                for (int r = 0; r < 4; ++r) {
                    float p = __expf(acc[r]);
                    rs[rb][r] += p;
                    Pw[(rb*16 + hi*4 + r)*PPW + cb*16 + lo] = f2h(p);
                }
            }
        }

        f16x8 pa[4];
        #pragma unroll
        for (int rb = 0; rb < 4; ++rb)
            pa[rb] = *(const f16x8*)&Pw[(rb*16 + lo)*PPW + hi*8];
        f16x8 bv[4];
        #pragma unroll
        for (int cd = 0; cd < 4; ++cd) {
            int row = cd*16 + lo;
            bv[cd] = *(const f16x8*)&VT[row*256 + ((s0 + hi*8) ^ ((row & 7) << 3))];
        }
        #pragma unroll
        for (int rb = 0; rb < 4; ++rb)
            #pragma unroll
            for (int cd = 0; cd < 4; ++cd)
                o[rb][cd] = __builtin_amdgcn_mfma_f32_16x16x32_f16(pa[rb], bv[cd], o[rb][cd], 0, 0, 0);
    }

    #pragma unroll
    for (int off = 1; off < 16; off <<= 1)
        #pragma unroll
        for (int rb = 0; rb < 4; ++rb)
            #pragma unroll
            for (int r = 0; r < 4; ++r)
                rs[rb][r] += __shfl_xor(rs[rb][r], off, 64);

    const float gate = 1.f / (1.f + __expf(-fg[0]));
    const float wt = 1.f - gate;
    #pragma unroll
    for (int rb = 0; rb < 4; ++rb) {
        #pragma unroll
        for (int r = 0; r < 4; ++r) {
            const int t = w*64 + rb*16 + hi*4 + r;
            const float sc = wt / rs[rb][r];
            unsigned short* yp = y + (((size_t)b*TT + t)*JJ + j)*CC + h*HD;
            #pragma unroll
            for (int cd = 0; cd < 4; ++cd)
                yp[cd*16 + lo] = f2h(o[rb][cd][r] * sc);
        }
    }
}

// ---------------- F1: DFT MFMA GEMM, f16 in -> f16 freq out in place --------
// V plane (blockIdx.y == 2) uses single-product W (post-softmax linear path).
#define XP 280

__global__ __launch_bounds__(256) void dft_k(
    unsigned short* __restrict__ planes, const unsigned short* __restrict__ Whi,
    const unsigned short* __restrict__ Wlo)
{
    __shared__ unsigned short Xh[64*XP];
    unsigned short* src = planes + (size_t)blockIdx.y*NQKV + (size_t)blockIdx.x*QTILE;
    const bool useLo = (blockIdx.y != 2);
    const int tid = threadIdx.x;
    const int w = tid >> 6;
    const int lane = tid & 63;
    const int qd = (tid >> 4) & 3;
    const int rr = tid & 15;
    const int lo = lane & 15, hi = lane >> 4;

    #pragma unroll
    for (int p = 0; p < 16; ++p) {
        const int t = p*16 + 4*w + qd;
        ushort4 x4 = *(const ushort4*)&src[t*64 + 4*rr];
        unsigned int a0 = x4.x, a1 = x4.y, a2 = x4.z, a3 = x4.w;
        unsigned int t01 = (unsigned)__shfl_xor((int)((qd&1) ? a0 : a1), 16, 64);
        unsigned int t23 = (unsigned)__shfl_xor((int)((qd&1) ? a2 : a3), 16, 64);
        if (qd&1) { a0 = t01; a2 = t23; } else { a1 = t01; a3 = t23; }
        unsigned int u01 = (unsigned)__shfl_xor((int)((qd&2) ? a0 : a2), 32, 64);
        unsigned int u23 = (unsigned)__shfl_xor((int)((qd&2) ? a1 : a3), 32, 64);
        if (qd&2) { a0 = u01; a1 = u23; } else { a2 = u01; a3 = u23; }
        const int dd = 4*rr + qd;
        const int tb = p*16 + 4*w;
        ushort4 hv;
        hv.x = (unsigned short)a0; hv.y = (unsigned short)a1;
        hv.z = (unsigned short)a2; hv.w = (unsigned short)a3;
        *(ushort4*)&Xh[dd*XP + tb] = hv;
    }
    __syncthreads();

    f32x4 acc[2][4];
    #pragma unroll
    for (int rb = 0; rb < 2; ++rb)
        #pragma unroll
        for (int cd = 0; cd < 4; ++cd) acc[rb][cd] = (f32x4){0.f,0.f,0.f,0.f};

    for (int ks = 0; ks < 8; ++ks) {
        const int k0 = ks*32;
        f16x8 ah[2], al[2];
        #pragma unroll
        for (int rb = 0; rb < 2; ++rb) {
            int r = w*32 + rb*16 + lo;
            ah[rb] = *(const f16x8*)&Whi[r*256 + k0 + hi*8];
            if (useLo) al[rb] = *(const f16x8*)&Wlo[r*256 + k0 + hi*8];
        }
        f16x8 bh[4];
        #pragma unroll
        for (int cd = 0; cd < 4; ++cd) {
            int d = cd*16 + lo;
            bh[cd] = *(const f16x8*)&Xh[d*XP + k0 + hi*8];
        }
        #pragma unroll
        for (int rb = 0; rb < 2; ++rb)
            #pragma unroll
            for (int cd = 0; cd < 4; ++cd) {
                acc[rb][cd] = __builtin_amdgcn_mfma_f32_16x16x32_f16(
                    ah[rb], bh[cd], acc[rb][cd], 0, 0, 0);
                if (useLo)
                    acc[rb][cd] = __builtin_amdgcn_mfma_f32_16x16x32_f16(
                        al[rb], bh[cd], acc[rb][cd], 0, 0, 0);
            }
    }

    #pragma unroll
    for (int rb = 0; rb < 2; ++rb) {
        #pragma unroll
        for (int r = 0; r < 4; ++r) {
            int row = w*32 + rb*16 + hi*4 + r;
            unsigned short* dst = (row < 64) ? (src + row*64)
                                             : (src + 4096 + (row-64)*64);
            #pragma unroll
            for (int cd = 0; cd < 4; ++cd)
                dst[cd*16 + lo] = f2h(acc[rb][cd][r]);
        }
    }
}

// ---------------- F2+F3 fused, all-MFMA (round-14 proven structure) ---------
#define FQP 72
#define XFP 136

__global__ __launch_bounds__(256) void freqtail_k(
    const unsigned short* __restrict__ qfp, const unsigned short* __restrict__ kfp,
    const unsigned short* __restrict__ vfp, const unsigned short* __restrict__ WIhi,
    const float* __restrict__ fg, unsigned short* __restrict__ y)
{
    __shared__ unsigned short S1[128*FQP];   // qf -> P -> XT
    __shared__ unsigned short S2[128*FQP];   // kf -> VFT

    const int tid = threadIdx.x;
    const int tile = blockIdx.x;
    const int b = tile / (HH*JJ);
    const int h = (tile / JJ) % HH;
    const int j = tile % JJ;
    const unsigned short* qf = qfp + (size_t)tile * QTILE;
    const unsigned short* kf = kfp + (size_t)tile * QTILE;
    const unsigned short* vf = vfp + (size_t)tile * QTILE;

    const int w = tid >> 6;
    const int lane = tid & 63;
    const int lo = lane & 15, hi = lane >> 4;
    const int comp = w >> 1;
    const int fr0 = (w & 1) * 32;

    #pragma unroll
    for (int p = 0; p < 4; ++p) {
        int e8 = (p*256 + tid) * 8;
        int row = e8 >> 6, col = e8 & 63;
        *(i16x8*)&S1[row*FQP + col] = *(const i16x8*)(qf + e8);
        *(i16x8*)&S2[row*FQP + col] = *(const i16x8*)(kf + e8);
    }
    __syncthreads();

    f32x4 accA[2][4], accB[2][4];
    #pragma unroll
    for (int rb = 0; rb < 2; ++rb)
        #pragma unroll
        for (int cb = 0; cb < 4; ++cb) {
            accA[rb][cb] = (f32x4){0.f,0.f,0.f,0.f};
            accB[rb][cb] = (f32x4){0.f,0.f,0.f,0.f};
        }
    #pragma unroll
    for (int ks = 0; ks < 2; ++ks) {
        f16x8 qA[2], qB[2];
        #pragma unroll
        for (int rb = 0; rb < 2; ++rb) {
            int fr = fr0 + rb*16 + lo;
            qA[rb] = *(const f16x8*)&S1[(comp*64 + fr)*FQP + ks*32 + hi*8];
            qB[rb] = *(const f16x8*)&S1[((1-comp)*64 + fr)*FQP + ks*32 + hi*8];
        }
        f16x8 kr[4], ki[4];
        #pragma unroll
        for (int cb = 0; cb < 4; ++cb) {
            int g = cb*16 + lo;
            kr[cb] = *(const f16x8*)&S2[g*FQP + ks*32 + hi*8];
            ki[cb] = *(const f16x8*)&S2[(64 + g)*FQP + ks*32 + hi*8];
        }
        #pragma unroll
        for (int rb = 0; rb < 2; ++rb)
            #pragma unroll
            for (int cb = 0; cb < 4; ++cb) {
                accA[rb][cb] = __builtin_amdgcn_mfma_f32_16x16x32_f16(
                    qA[rb], kr[cb], accA[rb][cb], 0, 0, 0);
                accB[rb][cb] = __builtin_amdgcn_mfma_f32_16x16x32_f16(
                    qB[rb], ki[cb], accB[rb][cb], 0, 0, 0);
            }
    }
    __syncthreads();

    const float sgn = comp ? -1.f : 1.f;
    float pv[2][4][4];
    float inv[2][4];
    #pragma unroll
    for (int rb = 0; rb < 2; ++rb) {
        #pragma unroll
        for (int r = 0; r < 4; ++r) {
            float m = -3.0e38f;
            #pragma unroll
            for (int cb = 0; cb < 4; ++cb) {
                float vv = accA[rb][cb][r] + sgn*accB[rb][cb][r];
                pv[rb][cb][r] = vv;
                m = fmaxf(m, vv);
            }
            #pragma unroll
            for (int off = 1; off < 16; off <<= 1)
                m = fmaxf(m, __shfl_xor(m, off, 64));
            float s = 0.f;
            #pragma unroll
            for (int cb = 0; cb < 4; ++cb) {
                float e = __expf(pv[rb][cb][r] - m);
                pv[rb][cb][r] = e;
                s += e;
            }
            #pragma unroll
            for (int off = 1; off < 16; off <<= 1)
                s += __shfl_xor(s, off, 64);
            inv[rb][r] = 1.f / s;
        }
    }
    #pragma unroll
    for (int rb = 0; rb < 2; ++rb)
        #pragma unroll
        for (int r = 0; r < 4; ++r)
            #pragma unroll
            for (int cb = 0; cb < 4; ++cb)
                S1[(w*32 + rb*16 + hi*4 + r)*FQP + cb*16 + lo] =
                    f2h(pv[rb][cb][r] * inv[rb][r]);

    #pragma unroll
    for (int p = 0; p < 4; ++p) {
        int e8 = (p*256 + tid) * 8;
        int srow = e8 >> 6;
        int c2 = srow >> 6, g = srow & 63, d0 = e8 & 63;
        i16x8 vv = *(const i16x8*)(vf + e8);
        #pragma unroll
        for (int e = 0; e < 8; ++e)
            S2[(c2*64 + d0 + e)*FQP + g] = (unsigned short)vv[e];
    }
    __syncthreads();

    f32x4 xA[2][4], xB[2][4];
    #pragma unroll
    for (int rb = 0; rb < 2; ++rb)
        #pragma unroll
        for (int cd = 0; cd < 4; ++cd) {
            xA[rb][cd] = (f32x4){0.f,0.f,0.f,0.f};
            xB[rb][cd] = (f32x4){0.f,0.f,0.f,0.f};
        }
    #pragma unroll
    for (int ks = 0; ks < 2; ++ks) {
        f16x8 pA[2], pB[2];
        #pragma unroll
        for (int rb = 0; rb < 2; ++rb) {
            int fr = fr0 + rb*16 + lo;
            pA[rb] = *(const f16x8*)&S1[fr*FQP + ks*32 + hi*8];
            pB[rb] = *(const f16x8*)&S1[(64 + fr)*FQP + ks*32 + hi*8];
        }
        f16x8 bA[4], bB[4];
        #pragma unroll
        for (int cd = 0; cd < 4; ++cd) {
            int d = cd*16 + lo;
            bA[cd] = *(const f16x8*)&S2[(comp*64 + d)*FQP + ks*32 + hi*8];
            bB[cd] = *(const f16x8*)&S2[((1-comp)*64 + d)*FQP + ks*32 + hi*8];
        }
        #pragma unroll
        for (int rb = 0; rb < 2; ++rb)
            #pragma unroll
            for (int cd = 0; cd < 4; ++cd) {
                xA[rb][cd] = __builtin_amdgcn_mfma_f32_16x16x32_f16(
                    pA[rb], bA[cd], xA[rb][cd], 0, 0, 0);
                xB[rb][cd] = __builtin_amdgcn_mfma_f32_16x16x32_f16(
                    pB[rb], bB[cd], xB[rb][cd], 0, 0, 0);
            }
    }
    __syncthreads();

    const float sgn2 = comp ? 1.f : -1.f;
    unsigned short* XT = S1;
    #pragma unroll
    for (int rb = 0; rb < 2; ++rb)
        #pragma unroll
        for (int cd = 0; cd < 4; ++cd)
            #pragma unroll
            for (int r = 0; r < 4; ++r) {
                int f = fr0 + rb*16 + hi*4 + r;
                int d = cd*16 + lo;
                XT[d*XFP + comp*64 + f] =
                    f2h(xA[rb][cd][r] + sgn2*xB[rb][cd][r]);
            }
    __syncthreads();

    f32x4 acc[4][4];
    #pragma unroll
    for (int rb = 0; rb < 4; ++rb)
        #pragma unroll
        for (int cd = 0; cd < 4; ++cd) acc[rb][cd] = (f32x4){0.f,0.f,0.f,0.f};

    #pragma unroll
    for (int ks = 0; ks < 4; ++ks) {
        const int k0 = ks*32;
        f16x8 ah[4];
        #pragma unroll
        for (int rb = 0; rb < 4; ++rb) {
            int row = w*64 + rb*16 + lo;
            ah[rb] = *(const f16x8*)&WIhi[row*128 + k0 + hi*8];
        }
        f16x8 bt[4];
        #pragma unroll
        for (int cd = 0; cd < 4; ++cd) {
            int d = cd*16 + lo;
            bt[cd] = *(const f16x8*)&XT[d*XFP + k0 + hi*8];
        }
        #pragma unroll
        for (int rb = 0; rb < 4; ++rb)
            #pragma unroll
            for (int cd = 0; cd < 4; ++cd)
                acc[rb][cd] = __builtin_amdgcn_mfma_f32_16x16x32_f16(
                    ah[rb], bt[cd], acc[rb][cd], 0, 0, 0);
    }

    const float gate = 1.f / (1.f + __expf(-fg[0]));
    #pragma unroll
    for (int rb = 0; rb < 4; ++rb) {
        #pragma unroll
        for (int r = 0; r < 4; ++r) {
            int t = w*64 + rb*16 + hi*4 + r;
            unsigned short* yp = y + (((size_t)b*TT + t)*JJ + j)*CC + h*HD;
            #pragma unroll
            for (int cd = 0; cd < 4; ++cd) {
                int d = cd*16 + lo;
                yp[d] = f2h(fmaf(gate, acc[rb][cd][r], h2f(yp[d])));
            }
        }
    }
}

// ---------------------------------------------------------------------------
extern "C" void kernel_launch(void* const* d_in, const int* in_sizes, int n_in,
                              void* d_out, int out_size, void* d_ws, size_t ws_size,
                              hipStream_t stream) {
    const float* x      = (const float*)d_in[0];
    const float* w_qkv  = (const float*)d_in[1];
    const float* w_proj = (const float*)d_in[2];
    const float* b_proj = (const float*)d_in[3];
    const float* fg     = (const float*)d_in[4];
    float* out = (float*)d_out;

    unsigned short* qp = (unsigned short*)d_ws;
    unsigned short* kp = qp + NQKV;
    unsigned short* vp = kp + NQKV;
    unsigned short* xh = vp + NQKV;
    unsigned short* y  = xh + NQKV;
    unsigned short* wph = y + NQKV;
    unsigned short* wqh = (unsigned short*)d_out;
    unsigned short* Whi  = wqh + 1536*512;   // 128*256
    unsigned short* Wlo  = Whi + 128*256;
    unsigned short* WIhi = Wlo + 128*256;    // 256*128

    conv16_k<<<2048, 256, 0, stream>>>(x, xh, NQKV/8);
    prep_k<<<768, 256, 0, stream>>>(w_qkv, w_proj, wqh, wph, Whi, Wlo, WIhi);

    gemm_qkv_k<<<6528, 256, 0, stream>>>(xh, wqh, qp, kp, vp);
    attn_time_k<<<NTILES, 256, 0, stream>>>(qp, kp, vp, fg, y);
    dft_k<<<dim3(NTILES, 3), 256, 0, stream>>>(qp, Whi, Wlo);
    freqtail_k<<<NTILES, 256, 0, stream>>>(qp, kp, vp, WIhi, fg, y);

    gemm_proj_k<<<2176, 256, 0, stream>>>(y, wph, b_proj, out);
}